// Round 10
// baseline (1781.324 us; speedup 1.0000x reference)
//
#include <hip/hip_runtime.h>
#include <hip/hip_bf16.h>
#include <math.h>

#define B_   64
#define T_   512
#define F_   256
#define ENC_ 256
#define P_   128
#define H_   256
#define K_   12
#define INV_TEMP 10.0f

typedef unsigned short u16;
typedef _Float16 half2v __attribute__((ext_vector_type(2)));
union U2H { unsigned int u; half2v h; };
typedef __attribute__((ext_vector_type(8))) short bf16x8;   // 8 bf16 = 4 VGPRs
typedef __attribute__((ext_vector_type(4))) float f32x4;    // MFMA C/D
typedef _Float16 f16x8 __attribute__((ext_vector_type(8))); // 8 f16 = 4 VGPRs
union BF8 { bf16x8 v; u16 e[8]; };

// ---------------- helpers ----------------------------------------------------
__device__ __forceinline__ float rcpf(float x) {
#if __has_builtin(__builtin_amdgcn_rcpf)
    return __builtin_amdgcn_rcpf(x);
#else
    return 1.f / x;
#endif
}
__device__ __forceinline__ u16 f2bf(float f) {   // RNE
    unsigned int u = __float_as_uint(f);
    unsigned int r = (u + 0x7fffu + ((u >> 16) & 1u)) >> 16;
    return (u16)r;
}
__device__ __forceinline__ float bf2f(u16 v) {
    return __uint_as_float(((unsigned int)v) << 16);
}
__device__ __forceinline__ float bflo(unsigned int u) { return __uint_as_float(u << 16); }
__device__ __forceinline__ float bfhi(unsigned int u) { return __uint_as_float(u & 0xffff0000u); }
__device__ __forceinline__ float wave_sum(float v) {
    #pragma unroll
    for (int o = 32; o > 0; o >>= 1) v += __shfl_down(v, o, 64);
    return v;
}

// ---------------- merged setup: weight conversions + fold + accum zero -------
__global__ __launch_bounds__(256) void setup_conv(const float* __restrict__ Wh,
                                                  _Float16* __restrict__ Wht,
                                                  const float* __restrict__ Wi,
                                                  u16* __restrict__ Wit,
                                                  const float* __restrict__ Wp,
                                                  u16* __restrict__ Wpt,
                                                  const float* __restrict__ We,
                                                  const float* __restrict__ be,
                                                  const float* __restrict__ Wpj,
                                                  const float* __restrict__ bpj,
                                                  u16* __restrict__ Wct,
                                                  float* __restrict__ bc,
                                                  float* __restrict__ accum) {
    int bid = blockIdx.x;
    if (bid < 192) {
        // Wht[g][k] = (f16)Wh[k][g]  (768x256 out of 256x768 in; 24x8 32x32 tiles)
        __shared__ float tile0[32][33];
        int g0 = (bid % 24) * 32, k0 = (bid / 24) * 32;
        int tx = threadIdx.x & 31, ty = threadIdx.x >> 5;
        #pragma unroll
        for (int i = 0; i < 32; i += 8)
            tile0[ty + i][tx] = Wh[(size_t)(k0 + ty + i) * 768 + g0 + tx];
        __syncthreads();
        #pragma unroll
        for (int i = 0; i < 32; i += 8)
            Wht[(size_t)(g0 + ty + i) * 256 + k0 + tx] = (_Float16)tile0[tx][ty + i];
    } else if (bid < 288) {
        __shared__ float tile[32][33];
        int b2 = bid - 192;                       // 0..95
        int n0 = (b2 % 24) * 32, k0 = (b2 / 24) * 32;
        int tx = threadIdx.x & 31, ty = threadIdx.x >> 5;
        #pragma unroll
        for (int i = 0; i < 32; i += 8)
            tile[ty + i][tx] = Wi[(size_t)(k0 + ty + i) * 768 + n0 + tx];
        __syncthreads();
        #pragma unroll
        for (int i = 0; i < 32; i += 8)
            Wit[(size_t)(n0 + ty + i) * 128 + k0 + tx] = f2bf(tile[tx][ty + i]);
    } else if (bid < 672) {
        __shared__ float tile2[32][33];
        int b3 = bid - 288;                       // 0..383
        int kq = b3 / 32, rem = b3 % 32;
        int h0 = (rem % 8) * 32, p0 = (rem / 8) * 32;
        int tx = threadIdx.x & 31, ty = threadIdx.x >> 5;
        #pragma unroll
        for (int i = 0; i < 32; i += 8)
            tile2[ty + i][tx] = Wp[(size_t)kq * H_ * P_ + (size_t)(h0 + ty + i) * P_ + p0 + tx];
        __syncthreads();
        #pragma unroll
        for (int i = 0; i < 32; i += 8)
            Wpt[(size_t)kq * P_ * H_ + (size_t)(p0 + ty + i) * H_ + h0 + tx] = f2bf(tile2[tx][ty + i]);
    } else {
        // fold: f = 2*(bid-672) + (tid>>7); p = tid&127
        int f = (bid - 672) * 2 + (threadIdx.x >> 7);
        int p = threadIdx.x & 127;
        if (f < F_) {
            float a = 0.f;
            for (int e = 0; e < ENC_; e++) a = fmaf(We[f * ENC_ + e], Wpj[e * P_ + p], a);
            Wct[(size_t)p * F_ + f] = f2bf(a);
        } else if (f == F_) {
            float a = bpj[p];
            for (int e = 0; e < ENC_; e++) a = fmaf(be[e], Wpj[e * P_ + p], a);
            bc[p] = a;
        } else {
            #pragma unroll
            for (int i = 0; i < 8; i++) accum[p * 8 + i] = 0.f;
        }
    }
}

// ---------------- MFMA GEMM, A = fp32 (converted in-register) ----------------
__global__ __launch_bounds__(256) void gemm_mfma_f32a(const float* __restrict__ A,
                                                      const u16* __restrict__ Bt,
                                                      const float* __restrict__ bias,
                                                      u16* __restrict__ Ch,
                                                      int N, int K) {
    int tid  = threadIdx.x;
    int w    = tid >> 6;
    int lane = tid & 63;
    int col  = lane & 15;
    int quad = lane >> 4;
    int bm = blockIdx.y * 64, bn = blockIdx.x * 128;

    f32x4 acc[8] = {};
    const float* arow = A + (size_t)(bm + w * 16 + col) * K;
    #pragma unroll
    for (int k0 = 0; k0 < K; k0 += 32) {
        float4 v0 = *(const float4*)(arow + k0 + quad * 8);
        float4 v1 = *(const float4*)(arow + k0 + quad * 8 + 4);
        BF8 af;
        af.e[0] = f2bf(v0.x); af.e[1] = f2bf(v0.y); af.e[2] = f2bf(v0.z); af.e[3] = f2bf(v0.w);
        af.e[4] = f2bf(v1.x); af.e[5] = f2bf(v1.y); af.e[6] = f2bf(v1.z); af.e[7] = f2bf(v1.w);
        #pragma unroll
        for (int nt = 0; nt < 8; nt++) {
            bf16x8 bf = *(const bf16x8*)(Bt + (size_t)(bn + nt * 16 + col) * K + k0 + quad * 8);
            acc[nt] = __builtin_amdgcn_mfma_f32_16x16x32_bf16(af.v, bf, acc[nt], 0, 0, 0);
        }
    }
    #pragma unroll
    for (int nt = 0; nt < 8; nt++) {
        int gn = bn + nt * 16 + col;
        float bv = bias[gn];
        #pragma unroll
        for (int r = 0; r < 4; r++) {
            int gm = bm + w * 16 + quad * 4 + r;
            Ch[(size_t)gm * N + gn] = f2bf(acc[nt][r] + bv);
        }
    }
}

// ---------------- MFMA GEMM, A = bf16, C = bf16 ------------------------------
__global__ __launch_bounds__(256) void gemm_mfma(const u16* __restrict__ A,
                                                 const u16* __restrict__ Bt,
                                                 const float* __restrict__ bias,
                                                 u16* __restrict__ Ch,
                                                 int N, int K) {
    int tid  = threadIdx.x;
    int w    = tid >> 6;
    int lane = tid & 63;
    int col  = lane & 15;
    int quad = lane >> 4;
    int bm = blockIdx.y * 64, bn = blockIdx.x * 128;

    f32x4 acc[8] = {};
    const u16* arow = A + (size_t)(bm + w * 16 + col) * K;
    #pragma unroll
    for (int k0 = 0; k0 < K; k0 += 32) {
        bf16x8 af = *(const bf16x8*)(arow + k0 + quad * 8);
        #pragma unroll
        for (int nt = 0; nt < 8; nt++) {
            bf16x8 bf = *(const bf16x8*)(Bt + (size_t)(bn + nt * 16 + col) * K + k0 + quad * 8);
            acc[nt] = __builtin_amdgcn_mfma_f32_16x16x32_bf16(af, bf, acc[nt], 0, 0, 0);
        }
    }
    #pragma unroll
    for (int nt = 0; nt < 8; nt++) {
        int gn = bn + nt * 16 + col;
        float bv = bias[gn];
        #pragma unroll
        for (int r = 0; r < 4; r++) {
            int gm = bm + w * 16 + quad * 4 + r;
            Ch[(size_t)gm * N + gn] = f2bf(acc[nt][r] + bv);
        }
    }
}

// ---------------- GRU scan (blocks 0..3, 16 batches each) + zsum (4..67) -----
// 16 REAL batches fill M=16 (r1's idea, r2's execution discipline):
//   A row = lane&15 = batch; A-frag = h[col][quad*8 + k0*32 ..] (ds_read_b128,
//   row stride 264 f16 = 528 B -> 2-way bank alias = free).
//   C row  = quad*4+r = batch; lane owns 8 DISTINCT outputs (4 batches x 2
//   gate-cols) -> zero redundant activation work (r1's 8x waste removed).
//   gi via per-lane GLOBAL prefetch regs (24 u16 loads/lane/t, 32B-contiguous
//   per 16-lane col group; no LDS staging, no conflicts — r1's killer removed).
//   Raw s_barrier + lgkmcnt(0) only (prefetch vmcnt never drained).
// Wall/t unchanged vs r2 (matrix pipe floor 1862 cyc is M-invariant) but CU
// footprint drops 64 -> 4, freeing 252 CUs (fusion target for next round).
#define GRUB_ 4

__global__ __attribute__((amdgpu_flat_work_group_size(512, 512)))
void gru_zsum_kernel(const u16* __restrict__ gi,
                     const _Float16* __restrict__ Wht,
                     const float* __restrict__ bhn,
                     u16* __restrict__ ch,
                     const u16* __restrict__ zh,
                     float* __restrict__ zsum) {
    __shared__ __align__(16) char smem[16896];
    int tid = threadIdx.x;          // 0..511

    if (blockIdx.x >= GRUB_) {
        // ---- zsum[b][p] = sum_{t=1..T-1} z[b][t][p], 16-way t-split ---------
        float (*part)[128] = (float (*)[128])smem;   // 8192 B
        int b   = blockIdx.x - GRUB_;
        int pg  = tid & 31;
        int g   = tid >> 5;
        const u16* zb = zh + (size_t)b * T_ * P_;
        float s0 = 0.f, s1 = 0.f, s2 = 0.f, s3 = 0.f;
        for (int t = 1 + g; t < T_; t += 16) {
            uint2 v = *(const uint2*)(zb + (size_t)t * P_ + pg * 4);
            s0 += bflo(v.x); s1 += bfhi(v.x);
            s2 += bflo(v.y); s3 += bfhi(v.y);
        }
        part[g][pg * 4 + 0] = s0; part[g][pg * 4 + 1] = s1;
        part[g][pg * 4 + 2] = s2; part[g][pg * 4 + 3] = s3;
        __syncthreads();
        if (tid < 128) {
            float s = 0.f;
            #pragma unroll
            for (int g2 = 0; g2 < 16; g2++) s += part[g2][tid];
            zsum[(size_t)b * P_ + tid] = s;
        }
        return;
    }

    // ---- GRU, 16 batches/block ----------------------------------------------
    _Float16* hbase = (_Float16*)smem;           // [2][16][264] f16 dbuf

    int lane = tid & 63, w = tid >> 6;
    int col  = lane & 15, quad = lane >> 4;
    int bb   = blockIdx.x * 16;
    int jj0  = w * 32 + col;                     // n2=0 gate-col; n2=1 adds 16

    // B fragments (identical to r2): wf[gate][n2][k0]
    f16x8 wf[3][2][8];
    #pragma unroll
    for (int g = 0; g < 3; g++)
        #pragma unroll
        for (int n2 = 0; n2 < 2; n2++) {
            const _Float16* src = Wht + (size_t)(g * 256 + jj0 + n2 * 16) * 256 + quad * 8;
            #pragma unroll
            for (int k0 = 0; k0 < 8; k0++)
                wf[g][n2][k0] = *(const f16x8*)(src + k0 * 32);
        }
    #pragma unroll
    for (int g = 0; g < 3; g++)
        #pragma unroll
        for (int n2 = 0; n2 < 2; n2++)
            #pragma unroll
            for (int k0 = 0; k0 < 8; k0++)
                asm volatile("" : "+v"(wf[g][n2][k0]));

    for (int i = tid; i < 8448; i += 512) hbase[i] = (_Float16)0.f;

    // per-lane outputs: batches qb = quad*4 + r (r=0..3), cols jj0 + n2*16
    const u16* gbr[4];
    u16*       cbr[4];
    #pragma unroll
    for (int r = 0; r < 4; r++) {
        gbr[r] = gi + (size_t)(bb + quad * 4 + r) * T_ * 768;
        cbr[r] = ch + (size_t)(bb + quad * 4 + r) * T_ * 256;
    }
    float bh0 = bhn[jj0], bh1 = bhn[jj0 + 16];
    float hold[2][4] = {};                       // [n2][r], fully unrolled use
    unsigned int pf[3][2][4];                    // [g][n2][r]

    #pragma unroll
    for (int g = 0; g < 3; g++)
        #pragma unroll
        for (int n2 = 0; n2 < 2; n2++)
            #pragma unroll
            for (int r = 0; r < 4; r++)
                pf[g][n2][r] = gbr[r][g * 256 + jj0 + n2 * 16];

    __syncthreads();     // h zeros visible (one-time full drain is fine)

    auto body = [&](int t, int c) {
        int n = c ^ 1;
        const _Float16* HC = hbase + c * (16 * 264);
        _Float16*       HN = hbase + n * (16 * 264);
        // gh = h(t-1) @ Wh : 48 MFMA; A-frag = h[batch=col][quad*8 + 32*k0]
        f32x4 aR0 = {}, aR1 = {}, aZ0 = {}, aZ1 = {}, aN0 = {}, aN1 = {};
        const _Float16* ha = HC + col * 264 + quad * 8;
        #pragma unroll
        for (int k0 = 0; k0 < 8; k0++) {
            f16x8 af = *(const f16x8*)(ha + k0 * 32);
            aR0 = __builtin_amdgcn_mfma_f32_16x16x32_f16(af, wf[0][0][k0], aR0, 0, 0, 0);
            aR1 = __builtin_amdgcn_mfma_f32_16x16x32_f16(af, wf[0][1][k0], aR1, 0, 0, 0);
            aZ0 = __builtin_amdgcn_mfma_f32_16x16x32_f16(af, wf[1][0][k0], aZ0, 0, 0, 0);
            aZ1 = __builtin_amdgcn_mfma_f32_16x16x32_f16(af, wf[1][1][k0], aZ1, 0, 0, 0);
            aN0 = __builtin_amdgcn_mfma_f32_16x16x32_f16(af, wf[2][0][k0], aN0, 0, 0, 0);
            aN1 = __builtin_amdgcn_mfma_f32_16x16x32_f16(af, wf[2][1][k0], aN1, 0, 0, 0);
        }
        // 8 distinct activations per lane: (batch quad*4+r, col jj0+n2*16)
        #pragma unroll
        for (int r = 0; r < 4; r++) {
            int rowoff = (quad * 4 + r) * 264;
            size_t tco = (size_t)t * 256;
            {   // n2 = 0
                float ir  = bf2f((u16)pf[0][0][r]);
                float iz  = bf2f((u16)pf[1][0][r]);
                float inn = bf2f((u16)pf[2][0][r]);
                float rg  = rcpf(1.f + __expf(-(ir + aR0[r])));
                float zg  = rcpf(1.f + __expf(-(iz + aZ0[r])));
                float xn  = inn + rg * (aN0[r] + bh0);
                float nn  = fmaf(2.f, rcpf(1.f + __expf(-2.f * xn)), -1.f);
                float hv  = (1.f - zg) * nn + zg * hold[0][r];
                hold[0][r] = hv;
                HN[rowoff + jj0] = (_Float16)hv;
                cbr[r][tco + jj0] = f2bf(hv);
            }
            {   // n2 = 1
                float ir  = bf2f((u16)pf[0][1][r]);
                float iz  = bf2f((u16)pf[1][1][r]);
                float inn = bf2f((u16)pf[2][1][r]);
                float rg  = rcpf(1.f + __expf(-(ir + aR1[r])));
                float zg  = rcpf(1.f + __expf(-(iz + aZ1[r])));
                float xn  = inn + rg * (aN1[r] + bh1);
                float nn  = fmaf(2.f, rcpf(1.f + __expf(-2.f * xn)), -1.f);
                float hv  = (1.f - zg) * nn + zg * hold[1][r];
                hold[1][r] = hv;
                HN[rowoff + jj0 + 16] = (_Float16)hv;
                cbr[r][tco + jj0 + 16] = f2bf(hv);
            }
        }
        // prefetch gi(t+1) AFTER pf consumed (counted vmcnt, never drained)
        if (t + 1 < T_) {
            size_t toff = (size_t)(t + 1) * 768;
            #pragma unroll
            for (int g = 0; g < 3; g++)
                #pragma unroll
                for (int n2 = 0; n2 < 2; n2++)
                    #pragma unroll
                    for (int r = 0; r < 4; r++)
                        pf[g][n2][r] = gbr[r][toff + g * 256 + jj0 + n2 * 16];
        }
        asm volatile("s_waitcnt lgkmcnt(0)" ::: "memory");
        __builtin_amdgcn_s_barrier();
        asm volatile("" ::: "memory");
    };

    #pragma unroll 1
    for (int t = 0; t < T_; t += 2) {
        body(t,     0);
        body(t + 1, 1);
    }
}

// ---------------- fused loss (r9: 2 blocks/CU + dbuf Zt, 1 barrier/iter) -----
__global__ __launch_bounds__(512, 4) void loss_fused(const u16* __restrict__ ch,
                                                     const u16* __restrict__ Wpt,
                                                     const float* __restrict__ bp,
                                                     const u16* __restrict__ zh,
                                                     const float* __restrict__ zsum,
                                                     float* __restrict__ accum) {
    __shared__ u16 Pst[128][136];        // 34816 B
    __shared__ u16 Zt[2][64][136];       // 34816 B (double buffer)
    __shared__ float sS[128];
    __shared__ float red[8];
    int k  = blockIdx.z + 1;
    int b  = blockIdx.y;
    int t0 = blockIdx.x * 128;
    int Tk = T_ - k;
    int tid  = threadIdx.x;
    int w    = tid >> 6;
    int lane = tid & 63;
    int col  = lane & 15;
    int quad = lane >> 4;
    const u16* zb = zh + (size_t)b * T_ * P_;
    const u16* zk = zb + (size_t)k * P_;

    // issue first 2 z-tiles ASAP (latency hidden under S_bk + phase 1)
    int rr  = tid >> 4;                  // 0..31
    int off = (tid & 15) * 8;
    uint4 a0 = *(const uint4*)(zk + (size_t)rr * P_ + off);
    uint4 b0 = *(const uint4*)(zk + (size_t)(rr + 32) * P_ + off);
    uint4 rA = *(const uint4*)(zk + (size_t)(64 + rr) * P_ + off);
    uint4 rB = *(const uint4*)(zk + (size_t)(64 + rr + 32) * P_ + off);

    // S_bk = zsum_b - sum_{t=1}^{k-1} z[t]
    if (tid < 128) {
        float s = zsum[(size_t)b * P_ + tid];
        for (int t = 1; t < k; t++) s -= bf2f(zb[(size_t)t * P_ + tid]);
        sS[tid] = s;
    }

    // ---- phase 1: Pst = bf16(ch-tile @ Wp[k] + bp[k]) -----------------------
    {
        f32x4 acc[8] = {};
        const u16* arow = ch + ((size_t)b * T_ + t0 + w * 16 + col) * H_;
        const u16* wk   = Wpt + (size_t)(k - 1) * P_ * H_;
        #pragma unroll
        for (int k0 = 0; k0 < 8; k0++) {
            bf16x8 af = *(const bf16x8*)(arow + k0 * 32 + quad * 8);
            #pragma unroll
            for (int nt = 0; nt < 8; nt++) {
                bf16x8 bf = *(const bf16x8*)(wk + (size_t)(nt * 16 + col) * H_ + k0 * 32 + quad * 8);
                acc[nt] = __builtin_amdgcn_mfma_f32_16x16x32_bf16(af, bf, acc[nt], 0, 0, 0);
            }
        }
        #pragma unroll
        for (int nt = 0; nt < 8; nt++) {
            float bias = bp[(size_t)(k - 1) * P_ + nt * 16 + col];
            #pragma unroll
            for (int r = 0; r < 4; r++)
                Pst[w * 16 + quad * 4 + r][nt * 16 + col] = f2bf(acc[nt][r] + bias);
        }
        // stage z tile 0 while phase-1 epilogue runs
        *(uint4*)&Zt[0][rr][off]      = a0;
        *(uint4*)&Zt[0][rr + 32][off] = b0;
    }
    __syncthreads();

    // ---- phase 2: flash LSE, double-buffered Zt, 1 barrier/iter -------------
    float mloc[4], sloc[4];
    #pragma unroll
    for (int r = 0; r < 4; r++) { mloc[r] = -INFINITY; sloc[r] = 0.f; }

    int nIter = (Tk + 63) >> 6;          // 8 for all k<=12
    int cbuf = 0;
    #pragma unroll 1
    for (int it = 0; it < nIter; ++it) {
        // write tile it+1 (loaded >=1 iter ago) into the other buffer
        if (it + 1 < nIter) {
            *(uint4*)&Zt[cbuf ^ 1][rr][off]      = rA;
            *(uint4*)&Zt[cbuf ^ 1][rr + 32][off] = rB;
        }
        // issue loads for tile it+2 (over-read past T lands in slack, masked)
        if (it + 2 < nIter) {
            const u16* zn = zk + (size_t)((it + 2) * 64) * P_;
            rA = *(const uint4*)(zn + (size_t)rr * P_ + off);
            rB = *(const uint4*)(zn + (size_t)(rr + 32) * P_ + off);
        }
        // MFMA on current buffer
        const u16* ztb = &Zt[cbuf][0][0];
        f32x4 acc[4] = {};
        #pragma unroll
        for (int k0 = 0; k0 < 4; k0++) {
            bf16x8 af = *(const bf16x8*)(&Pst[w * 16 + col][k0 * 32 + quad * 8]);
            #pragma unroll
            for (int nt = 0; nt < 4; nt++) {
                bf16x8 bf = *(const bf16x8*)(ztb + (size_t)(nt * 16 + col) * 136 + k0 * 32 + quad * 8);
                acc[nt] = __builtin_amdgcn_mfma_f32_16x16x32_bf16(af, bf, acc[nt], 0, 0, 0);
            }
        }
        int ct = it * 64;
        #pragma unroll
        for (int r = 0; r < 4; r++) {
            float l[4];
            float tmax = -INFINITY;
            #pragma unroll
            for (int nt = 0; nt < 4; nt++) {
                bool valid = (ct + nt * 16 + col) < Tk;
                l[nt] = valid ? acc[nt][r] * INV_TEMP : -INFINITY;
                tmax = fmaxf(tmax, l[nt]);
            }
            float mnew = fmaxf(mloc[r], tmax);
            float e = __expf(l[0] - mnew) + __expf(l[1] - mnew)
                    + __expf(l[2] - mnew) + __expf(l[3] - mnew);
            sloc[r] = sloc[r] * __expf(mloc[r] - mnew) + e;
            mloc[r] = mnew;
        }
        asm volatile("s_waitcnt lgkmcnt(0)" ::: "memory");
        __builtin_amdgcn_s_barrier();
        asm volatile("" ::: "memory");
        cbuf ^= 1;
    }
    #pragma unroll
    for (int r = 0; r < 4; r++) {
        #pragma unroll
        for (int o = 1; o < 16; o <<= 1) {
            float mo = __shfl_xor(mloc[r], o, 64);
            float so = __shfl_xor(sloc[r], o, 64);
            float mn = fmaxf(mloc[r], mo);
            sloc[r] = sloc[r] * __expf(mloc[r] - mn) + so * __expf(mo - mn);
            mloc[r] = mn;
        }
    }
    float tkinv = INV_TEMP / (float)Tk;
    float scale = 1.0f / ((float)K_ * (float)B_ * (float)Tk);
    float bs = 0.f;
    #pragma unroll
    for (int r = 0; r < 4; r++) {
        int row = w * 16 + quad * 4 + r;
        BF8 pv;
        pv.v = *(const bf16x8*)(&Pst[row][col * 8]);
        float d = 0.f;
        #pragma unroll
        for (int m = 0; m < 8; m++) d = fmaf(bf2f(pv.e[m]), sS[col * 8 + m], d);
        #pragma unroll
        for (int o = 1; o < 16; o <<= 1) d += __shfl_xor(d, o, 64);
        int gr = t0 + row;
        if (gr < Tk) bs += mloc[r] + __logf(sloc[r]) - d * tkinv;
    }
    if (col != 0) bs = 0.f;
    bs = wave_sum(bs);
    if (lane == 0) red[w] = bs;
    __syncthreads();
    if (tid == 0) {
        float tot = 0.f;
        #pragma unroll
        for (int i = 0; i < 8; i++) tot += red[i];
        atomicAdd(&accum[(blockIdx.x * 809 + b * 67 + blockIdx.z * 131) & 1023],
                  tot * scale);
    }
}

__global__ void finalize(const float* __restrict__ accum, float* __restrict__ out) {
    int tid = threadIdx.x;
    __shared__ float red[4];
    float v = 0.f;
    for (int i = tid; i < 1024; i += 256) v += accum[i];
    float sres = wave_sum(v);
    if ((tid & 63) == 0) red[tid >> 6] = sres;
    __syncthreads();
    if (tid == 0) out[0] = red[0] + red[1] + red[2] + red[3];
}

// ---------------- launch -----------------------------------------------------
extern "C" void kernel_launch(void* const* d_in, const int* in_sizes, int n_in,
                              void* d_out, int out_size, void* d_ws, size_t ws_size,
                              hipStream_t stream) {
    const float* x      = (const float*)d_in[0];
    const float* W_enc  = (const float*)d_in[1];
    const float* b_enc  = (const float*)d_in[2];
    const float* W_proj = (const float*)d_in[3];
    const float* b_proj = (const float*)d_in[4];
    const float* Wi     = (const float*)d_in[5];
    const float* bi     = (const float*)d_in[6];
    const float* Wh     = (const float*)d_in[7];
    const float* bhn    = (const float*)d_in[8];
    const float* Wp     = (const float*)d_in[9];
    const float* bp     = (const float*)d_in[10];
    float* out = (float*)d_out;

    // layout (float offsets)
    float* ws    = (float*)d_ws;
    float* bc    = ws;                          // 128
    float* accum = bc + 128;                    // 1024 -> end 1152
    _Float16* Wht = (_Float16*)(ws + 1152);     // 196608 f16 = 98304 fl -> end 99456
    u16* Wct     = (u16*)(ws + 99456);          // 16384 fl -> end 115840
    u16* Wit     = (u16*)(ws + 115840);         // 49152 fl -> end 164992
    u16* Wpt     = (u16*)(ws + 164992);         // 196608 fl -> end 361600
    u16* zh      = (u16*)(ws + 361600);         // 2097152 fl -> end 2458752
    float* zsum  = ws + 2458752;                // 8192 fl (doubles as zh over-read slack) -> end 2466944
    u16* gi      = (u16*)(ws + 2466944);        // 12582912 fl -> end 15049856
    u16* ch      = (u16*)(ws + 15049856);       // 4194304 fl -> end 19244160 (~77 MB)

    const int MT = B_ * T_;                     // 32768

    // merged setup: all weight conversions + fold + accum zero (801 blocks)
    setup_conv<<<801, 256, 0, stream>>>(Wh, Wht, Wi, Wit, Wp, Wpt,
                                        W_enc, b_enc, W_proj, b_proj, Wct, bc, accum);
    // zh = bf16(x @ Wct^T + bc)   (M=32768, N=128, K=256; A converted in-reg)
    gemm_mfma_f32a<<<dim3(1, MT / 64), 256, 0, stream>>>(x, Wct, bc, zh, P_, F_);
    // gi = bf16(zh @ Wit^T + bi)  (M=32768, N=768, K=128)
    gemm_mfma<<<dim3(6, MT / 64), 256, 0, stream>>>(zh, Wit, bi, gi, 3 * H_, P_);
    // GRU scan, 16 batches/block (blocks 0..3) + zsum (4..67)
    gru_zsum_kernel<<<GRUB_ + B_, 512, 0, stream>>>(gi, Wht, bhn, ch, zh, zsum);
    // fused loss: r9 structure (2 blocks/CU, dbuf Zt, 1 barrier/iter)
    loss_fused<<<dim3(4, B_, K_), 512, 0, stream>>>(ch, Wpt, bp, zh, zsum, accum);
    finalize<<<1, 256, 0, stream>>>(accum, out);
}